// Round 17
// baseline (318.579 us; speedup 1.0000x reference)
//
#include <hip/hip_runtime.h>
#include <hip/hip_bf16.h>

#define Mdim 8192
#define Ndim 16384
#define Ennz 2097152
#define Bsz 8
#define Jit 3
#define IMG 128
#define RCAP 512
#define CCAP 256
#define PSTRIDE 270336   // E/8 + slack
#define QSTRIDE 135168   // E/16 + slack

typedef __attribute__((ext_vector_type(8))) short bf8_t;
typedef __attribute__((ext_vector_type(4))) float f4_t;

__device__ __forceinline__ short f2b(float f){
    __hip_bfloat16 h = __float2bfloat16(f);
    return *reinterpret_cast<short*>(&h);
}
__device__ __forceinline__ float bval(unsigned e){
    return __uint_as_float(e & 0xFFFF0000u);
}

// ---- prep: bf16 weight conversion + zero all counters ----
__global__ void k_prep(const float* __restrict__ W2, const float* __restrict__ W3,
                       short* __restrict__ w2p, short* __restrict__ w3p,
                       int* bin_pos, int* cnts){
    int i = blockIdx.x*256 + threadIdx.x;     // grid 108*256 = 27648
    if(i < 24) bin_pos[i] = 0;
    if(i < 24576) cnts[i] = 0;                // row_cnt(8192)+col_cnt(16384) adjacent
    if(i < 27648){
        int j = i / 9216, idx = i - j*9216;
        int kk = idx >> 10, rem = idx & 1023;
        int ic = rem >> 5, oc = rem & 31;
        w2p[(size_t)j*11520 + (kk*32 + oc)*40 + ic] = f2b(W2[i]);
    }
    if(i < 864) w3p[i] = f2b(W3[i]);
}

// ---- partition COO into 8 row-group + 16 col-group streams.
// Per-wave counters/offsets (cnt[4][24]) kill the 32-way LDS same-address
// atomic serialization of the single-array version.
__global__ __launch_bounds__(256) void k_part(const float* __restrict__ vals,
        const int* __restrict__ rows, const int* __restrict__ cols,
        int* bin_pos, uint2* __restrict__ Pst, uint2* __restrict__ Qst){
    __shared__ int cnt[4][24];
    __shared__ int woff[4][24];
    __shared__ int tot[24], start[24], gbase[24];
    __shared__ uint2 stage[4096];
    int t = threadIdx.x, wv = t >> 6;
    if(t < 96) ((int*)cnt)[t] = 0;
    __syncthreads();
    int base = blockIdx.x * 2048;
    int r[8], c[8]; float v[8];
    #pragma unroll
    for(int k = 0; k < 8; k++){
        int e = base + k*256 + t;
        r[k] = rows[e]; c[k] = cols[e]; v[k] = vals[e];
        atomicAdd(&cnt[wv][r[k] >> 10], 1);
        atomicAdd(&cnt[wv][8 + (c[k] >> 10)], 1);
    }
    __syncthreads();
    if(t < 24) tot[t] = cnt[0][t] + cnt[1][t] + cnt[2][t] + cnt[3][t];
    __syncthreads();
    if(t == 0){
        int s = 0;
        for(int q = 0; q < 8; q++){ start[q] = s; s += tot[q]; }
        s = 2048;
        for(int q = 8; q < 24; q++){ start[q] = s; s += tot[q]; }
    }
    if(t < 24) gbase[t] = atomicAdd(&bin_pos[t], tot[t]);
    __syncthreads();
    if(t < 96){
        int w = t / 24, b = t - w*24;
        int off = start[b];
        for(int w2 = 0; w2 < w; w2++) off += cnt[w2][b];
        woff[w][b] = off;
    }
    __syncthreads();
    #pragma unroll
    for(int k = 0; k < 8; k++){
        int pb = r[k] >> 10;
        int p = atomicAdd(&woff[wv][pb], 1);
        stage[p] = make_uint2(((unsigned)(r[k] & 1023) << 14) | (unsigned)c[k],
                              __float_as_uint(v[k]));
        int qb = 8 + (c[k] >> 10);
        int q = atomicAdd(&woff[wv][qb], 1);
        stage[q] = make_uint2(((unsigned)(c[k] & 1023) << 13) | (unsigned)r[k],
                              __float_as_uint(v[k]));
    }
    __syncthreads();
    for(int q = 0; q < 8; q++){
        int len = tot[q];
        uint2* dst = Pst + (size_t)q*PSTRIDE + gbase[q];
        for(int k = t; k < len; k += 256) dst[k] = stage[start[q] + k];
    }
    for(int q = 8; q < 24; q++){
        int len = tot[q];
        uint2* dst = Qst + (size_t)(q-8)*QSTRIDE + gbase[q];
        for(int k = t; k < len; k += 256) dst[k] = stage[start[q] + k];
    }
}

// ---- merged: scat_r | scat_c | init; buckets are 4 B entries (bf16 val | idx) ----
__global__ __launch_bounds__(256) void k_scat(const uint2* __restrict__ Pst,
        const uint2* __restrict__ Qst, const int* __restrict__ bin_pos,
        int* row_cnt, int* col_cnt, unsigned* __restrict__ rp, unsigned* __restrict__ cp,
        const float* __restrict__ z_in, const float* __restrict__ u,
        float* __restrict__ z_cur, float* __restrict__ zu_T){
    __shared__ int cnt[1024], curs[1024];
    int t = threadIdx.x;
    int bid = blockIdx.x;
    if(bid >= 768){          // ---- init branch ----
        int i = (bid - 768)*256 + t;
        int n = i >> 3, b = i & 7;
        float z = z_in[b*Ndim + n];
        z_cur[b*Ndim + n] = z;
        zu_T[i] = z * u[b*Ndim + n];
        return;
    }
    if(bid < 256){           // ---- scatter rows ----
        int g = bid & 7, chunk = bid >> 3;
        int len = bin_pos[g];
        int s0 = (int)(((long long)chunk * len) >> 5);
        int s1 = (int)(((long long)(chunk+1) * len) >> 5);
        for(int i = t; i < 1024; i += 256) cnt[i] = 0;
        __syncthreads();
        const uint2* base = Pst + (size_t)g*PSTRIDE;
        for(int k = s0 + t; k < s1; k += 256)
            atomicAdd(&cnt[base[k].x >> 14], 1);
        __syncthreads();
        for(int i = t; i < 1024; i += 256)
            curs[i] = atomicAdd(&row_cnt[g*1024 + i], cnt[i]);
        __syncthreads();
        for(int k = s0 + t; k < s1; k += 256){
            uint2 e = base[k];
            int r_l = e.x >> 14;
            int slot = atomicAdd(&curs[r_l], 1);
            if(slot < RCAP)
                rp[(size_t)(g*1024 + r_l)*RCAP + slot] =
                    (((unsigned)(unsigned short)f2b(__uint_as_float(e.y))) << 16)
                    | (e.x & 0x3FFFu);
        }
    } else {                 // ---- scatter cols ----
        int bc = bid - 256;
        int g = bc & 15, chunk = bc >> 4;
        int len = bin_pos[8 + g];
        int s0 = (int)(((long long)chunk * len) >> 5);
        int s1 = (int)(((long long)(chunk+1) * len) >> 5);
        for(int i = t; i < 1024; i += 256) cnt[i] = 0;
        __syncthreads();
        const uint2* base = Qst + (size_t)g*QSTRIDE;
        for(int k = s0 + t; k < s1; k += 256)
            atomicAdd(&cnt[base[k].x >> 13], 1);
        __syncthreads();
        for(int i = t; i < 1024; i += 256)
            curs[i] = atomicAdd(&col_cnt[g*1024 + i], cnt[i]);
        __syncthreads();
        for(int k = s0 + t; k < s1; k += 256){
            uint2 e = base[k];
            int c_l = e.x >> 13;
            int slot = atomicAdd(&curs[c_l], 1);
            if(slot < CCAP)
                cp[(size_t)(g*1024 + c_l)*CCAP + slot] =
                    (((unsigned)(unsigned short)f2b(__uint_as_float(e.y))) << 16)
                    | (e.x & 0x1FFFu);
        }
    }
}

// ---- gather-SpMM 1 (+ zero ssq_part[512]) ----
__global__ void k_spmm1g(const unsigned* __restrict__ rp, const int* __restrict__ row_cnt,
                         const float* __restrict__ y, const float* __restrict__ zu_T,
                         float* __restrict__ resid_T, float* __restrict__ ssq_part){
    if(blockIdx.x == 0){
        ssq_part[threadIdx.x] = 0.f;
        ssq_part[256 + threadIdx.x] = 0.f;
    }
    int m = (blockIdx.x*256 + threadIdx.x) >> 6;
    int lane = threadIdx.x & 63;
    int n_nz = min(row_cnt[m], RCAP);
    int b = lane & 7, ks = lane >> 3;
    const unsigned* base = rp + (size_t)m*RCAP;
    float acc = 0.f;
    for(int k = ks*4; k < n_nz; k += 32){
        uint4 e = *(const uint4*)(base + k);
        float w0 = bval(e.x);
        float w1 = (k+1 < n_nz) ? bval(e.y) : 0.f;
        float w2 = (k+2 < n_nz) ? bval(e.z) : 0.f;
        float w3 = (k+3 < n_nz) ? bval(e.w) : 0.f;
        acc = fmaf(w0, zu_T[(e.x & 0x3FFFu)*8 + b], acc);
        acc = fmaf(w1, zu_T[(e.y & 0x3FFFu)*8 + b], acc);
        acc = fmaf(w2, zu_T[(e.z & 0x3FFFu)*8 + b], acc);
        acc = fmaf(w3, zu_T[(e.w & 0x3FFFu)*8 + b], acc);
    }
    acc += __shfl_xor(acc, 8);
    acc += __shfl_xor(acc, 16);
    acc += __shfl_xor(acc, 32);
    if(ks == 0)
        resid_T[m*8 + b] = y[b*Mdim + m] - acc;
}

// ---- gather-SpMM 2 with fused norm partial reduction ----
__global__ void k_spmm2g(const unsigned* __restrict__ cp, const int* __restrict__ col_cnt,
                         const float* __restrict__ resid_T, const float* __restrict__ u,
                         float* __restrict__ v_T, float* __restrict__ ssq_part){
    __shared__ float sred[8];
    int t = threadIdx.x;
    if(t < 8) sred[t] = 0.f;
    __syncthreads();
    int n = (blockIdx.x*256 + t) >> 6;
    int lane = t & 63;
    int n_nz = min(col_cnt[n], CCAP);
    int b = lane & 7, ks = lane >> 3;
    const unsigned* base = cp + (size_t)n*CCAP;
    float acc = 0.f;
    for(int k = ks*4; k < n_nz; k += 32){
        uint4 e = *(const uint4*)(base + k);
        float w0 = bval(e.x);
        float w1 = (k+1 < n_nz) ? bval(e.y) : 0.f;
        float w2 = (k+2 < n_nz) ? bval(e.z) : 0.f;
        float w3 = (k+3 < n_nz) ? bval(e.w) : 0.f;
        acc = fmaf(w0, resid_T[(e.x & 0x1FFFu)*8 + b], acc);
        acc = fmaf(w1, resid_T[(e.y & 0x1FFFu)*8 + b], acc);
        acc = fmaf(w2, resid_T[(e.z & 0x1FFFu)*8 + b], acc);
        acc = fmaf(w3, resid_T[(e.w & 0x1FFFu)*8 + b], acc);
    }
    acc += __shfl_xor(acc, 8);
    acc += __shfl_xor(acc, 16);
    acc += __shfl_xor(acc, 32);
    if(ks == 0){
        v_T[n*8 + b] = acc;
        float uv = u[b*Ndim + n] * acc;
        atomicAdd(&sred[b], uv*uv);
    }
    __syncthreads();
    if(t < 8) atomicAdd(&ssq_part[(blockIdx.x & 63)*8 + t], sred[t]);
}

// ---- fused conv1+conv2+conv3, 2 tiles per block (1024 blocks, 3 blocks/CU) ----
__global__ __launch_bounds__(256) void k_conv123(
        const float* __restrict__ z_src, const float* __restrict__ u,
        const float* __restrict__ v_T, const float* __restrict__ ssq_part,
        const float* __restrict__ etas, const float* __restrict__ W1,
        const short* __restrict__ w2p, const short* __restrict__ w3p,
        int j, float* __restrict__ z_dst, float* __restrict__ zu_T){
    __shared__ short w2t[9*32*40];
    __shared__ short x1t[144*40];
    __shared__ short x2t[100*40];
    __shared__ float w1s[288];
    __shared__ short w3b[288];
    __shared__ float r14[196];
    __shared__ float sc_lds;
    int t = threadIdx.x;
    int blk = blockIdx.x;                // 1024 blocks: bb = blk>>7, tgroup = blk&127
    int bb = blk >> 7, tgroup = blk & 127;

    for(int idx = t; idx < 1440; idx += 256)
        ((uint4*)w2t)[idx] = ((const uint4*)(w2p + (size_t)j*11520))[idx];
    for(int idx = t; idx < 288; idx += 256){
        w1s[idx] = W1[j*288 + idx];
        w3b[idx] = w3p[j*288 + idx];
    }
    if(t < 64){              // reduce ssq_part -> scale for this sample
        float sv = ssq_part[t*8 + bb];
        #pragma unroll
        for(int off = 32; off > 0; off >>= 1) sv += __shfl_xor(sv, off);
        if(t == 0) sc_lds = etas[j] / fmaxf(1.0f, sqrtf(sv));
    }
    __syncthreads();
    float sc = sc_lds;

    int wv = t >> 6, lane = t & 63, mm = lane & 15, q = lane >> 4;

    for(int tt = 0; tt < 2; tt++){
        int tile = tgroup*2 + tt;
        int oy0 = (tile >> 4)*8, ox0 = (tile & 15)*8;

        if(t < 196){
            int yy = t/14, xx = t%14;
            int gy = oy0 + yy - 3, gx = ox0 + xx - 3;
            float val = 0.f;
            if((unsigned)gy < 128u && (unsigned)gx < 128u){
                int n = gy*IMG + gx;
                int idx = bb*Ndim + n;
                val = z_src[idx] - sc * u[idx] * v_T[n*8 + bb];
            }
            r14[t] = val;
        }
        __syncthreads();

        // conv1 -> x1t bf16
        for(int idx = t; idx < 2304; idx += 256){
            int ocp = idx & 15, p = idx >> 4;
            int py = p/12, px = p%12;
            int gy = oy0 + py - 2, gx = ox0 + px - 2;
            float a0 = 0.f, a1 = 0.f;
            if((unsigned)gy < 128u && (unsigned)gx < 128u){
                #pragma unroll
                for(int ky = 0; ky < 3; ky++)
                    #pragma unroll
                    for(int kx = 0; kx < 3; kx++){
                        float rv = r14[(py+ky)*14 + (px+kx)];
                        a0 = fmaf(rv, w1s[(ky*3+kx)*32 + 2*ocp],     a0);
                        a1 = fmaf(rv, w1s[(ky*3+kx)*32 + 2*ocp + 1], a1);
                    }
                a0 = fmaxf(a0, 0.f); a1 = fmaxf(a1, 0.f);
            }
            unsigned pack = (unsigned short)f2b(a0) | ((unsigned)(unsigned short)f2b(a1) << 16);
            ((unsigned*)x1t)[p*20 + ocp] = pack;
        }
        __syncthreads();

        // conv2 MFMA -> x2t
        #pragma unroll
        for(int rnd = 0; rnd < 2; rnd++){
            int p = rnd*64 + wv*16 + mm;
            int pp = min(p, 99);
            int py2 = pp/10, px2 = pp%10;
            f4_t acc0 = {0.f,0.f,0.f,0.f}, acc1 = {0.f,0.f,0.f,0.f};
            #pragma unroll
            for(int kk = 0; kk < 9; kk++){
                int ky = kk/3, kx = kk%3;
                bf8_t a  = *(const bf8_t*)&x1t[((py2+ky)*12 + (px2+kx))*40 + q*8];
                bf8_t b0 = *(const bf8_t*)&w2t[(kk*32 + mm)*40 + q*8];
                bf8_t b1 = *(const bf8_t*)&w2t[(kk*32 + 16 + mm)*40 + q*8];
                acc0 = __builtin_amdgcn_mfma_f32_16x16x32_bf16(a, b0, acc0, 0, 0, 0);
                acc1 = __builtin_amdgcn_mfma_f32_16x16x32_bf16(a, b1, acc1, 0, 0, 0);
            }
            #pragma unroll
            for(int reg = 0; reg < 4; reg++){
                int pw = rnd*64 + wv*16 + q*4 + reg;
                if(pw < 100){
                    int py = pw/10, px = pw%10;
                    int gy = oy0 + py - 1, gx = ox0 + px - 1;
                    bool in = ((unsigned)gy < 128u) && ((unsigned)gx < 128u);
                    x2t[pw*40 + mm]      = in ? f2b(fmaxf(acc0[reg], 0.f)) : (short)0;
                    x2t[pw*40 + mm + 16] = in ? f2b(fmaxf(acc1[reg], 0.f)) : (short)0;
                }
            }
        }
        __syncthreads();

        // conv3 MFMA (col 0) + epilogue
        int p3 = wv*16 + mm;
        int py3 = p3 >> 3, px3 = p3 & 7;
        f4_t acc = {0.f,0.f,0.f,0.f};
        #pragma unroll
        for(int kk = 0; kk < 9; kk++){
            int ky = kk/3, kx = kk%3;
            bf8_t a = *(const bf8_t*)&x2t[((py3+ky)*10 + (px3+kx))*40 + q*8];
            bf8_t bf;
            #pragma unroll
            for(int jj = 0; jj < 8; jj++)
                bf[jj] = (mm == 0) ? w3b[kk*32 + q*8 + jj] : (short)0;
            acc = __builtin_amdgcn_mfma_f32_16x16x32_bf16(a, bf, acc, 0, 0, 0);
        }
        if(mm == 0){
            #pragma unroll
            for(int reg = 0; reg < 4; reg++){
                int po = wv*16 + q*4 + reg;
                int py = po >> 3, px = po & 7;
                int gy = oy0 + py, gx = ox0 + px;
                int n = gy*IMG + gx;
                int idx = bb*Ndim + n;
                float r = r14[(py+3)*14 + (px+3)];
                float znew = fmaxf(r + acc[reg], 0.f);
                z_dst[idx] = znew;
                zu_T[n*8 + bb] = znew * u[idx];
            }
        }
        __syncthreads();   // protect r14/x1t/x2t reuse next tile
    }
}

extern "C" void kernel_launch(void* const* d_in, const int* in_sizes, int n_in,
                              void* d_out, int out_size, void* d_ws, size_t ws_size,
                              hipStream_t stream){
    const float* A_vals = (const float*)d_in[0];
    const int* A_rows = (const int*)d_in[1];
    const int* A_cols = (const int*)d_in[2];
    const float* z_in = (const float*)d_in[3];
    const float* u    = (const float*)d_in[4];
    const float* y    = (const float*)d_in[5];
    const float* W1   = (const float*)d_in[6];
    const float* W2   = (const float*)d_in[7];
    const float* W3   = (const float*)d_in[8];
    const float* etas = (const float*)d_in[9];

    float* ws = (float*)d_ws;
    float* zA      = ws;  ws += Bsz*Ndim;      // ping
    float* zB      = ws;  ws += Bsz*Ndim;      // pong
    float* zu_T    = ws;  ws += Ndim*8;
    float* v_T     = ws;  ws += Ndim*8;
    float* resid_T = ws;  ws += Mdim*8;
    float* ssq_part= ws;  ws += 512;
    int*   bin_pos = (int*)ws; ws += 32;
    int*   row_cnt = (int*)ws; ws += Mdim;     // col_cnt adjacent after
    int*   col_cnt = (int*)ws; ws += Ndim;
    short* w2p     = (short*)ws; ws += 3*11520/2;
    short* w3p     = (short*)ws; ws += 3*288/2 + 8;
    unsigned* rp = (unsigned*)ws; ws += (size_t)Mdim*RCAP;   // 16.8 MB
    unsigned* cp = (unsigned*)ws; ws += (size_t)Ndim*CCAP;   // 16.8 MB
    uint2* Pst = (uint2*)ws;  ws += (size_t)8*PSTRIDE*2;     // 17.3 MB
    uint2* Qst = (uint2*)ws;                                  // 17.3 MB

    k_prep<<<108, 256, 0, stream>>>(W2, W3, w2p, w3p, bin_pos, row_cnt);
    k_part<<<Ennz/2048, 256, 0, stream>>>(A_vals, A_rows, A_cols, bin_pos, Pst, Qst);
    k_scat<<<1280, 256, 0, stream>>>(Pst, Qst, bin_pos, row_cnt, col_cnt, rp, cp,
                                     z_in, u, zA, zu_T);

    for(int j = 0; j < Jit; j++){
        k_spmm1g<<<Mdim/4, 256, 0, stream>>>(rp, row_cnt, y, zu_T, resid_T, ssq_part);
        k_spmm2g<<<Ndim/4, 256, 0, stream>>>(cp, col_cnt, resid_T, u, v_T, ssq_part);
        const float* zsrc = (j & 1) ? zB : zA;           // j=0:A, j=1:B, j=2:A
        float* zdst = (j == Jit-1) ? (float*)d_out : ((j & 1) ? zA : zB);
        k_conv123<<<1024, 256, 0, stream>>>(zsrc, u, v_T, ssq_part, etas,
                                            W1, w2p, w3p, j, zdst, zu_T);
    }
}

// Round 18
// 313.828 us; speedup vs baseline: 1.0151x; 1.0151x over previous
//
#include <hip/hip_runtime.h>
#include <hip/hip_bf16.h>

#define Mdim 8192
#define Ndim 16384
#define Ennz 2097152
#define Bsz 8
#define Jit 3
#define IMG 128
#define RCAP 512
#define CCAP 256
#define PSTRIDE 270336   // E/8 + slack
#define QSTRIDE 135168   // E/16 + slack

typedef __attribute__((ext_vector_type(8))) short bf8_t;
typedef __attribute__((ext_vector_type(4))) float f4_t;

__device__ __forceinline__ short f2b(float f){
    __hip_bfloat16 h = __float2bfloat16(f);
    return *reinterpret_cast<short*>(&h);
}
__device__ __forceinline__ float bval(unsigned e){
    return __uint_as_float(e & 0xFFFF0000u);
}

// ---- prep: bf16 weight conversion + zero all counters ----
__global__ void k_prep(const float* __restrict__ W2, const float* __restrict__ W3,
                       short* __restrict__ w2p, short* __restrict__ w3p,
                       int* bin_pos, int* cnts){
    int i = blockIdx.x*256 + threadIdx.x;     // grid 108*256 = 27648
    if(i < 24) bin_pos[i] = 0;
    if(i < 24576) cnts[i] = 0;                // row_cnt(8192)+col_cnt(16384) adjacent
    if(i < 27648){
        int j = i / 9216, idx = i - j*9216;
        int kk = idx >> 10, rem = idx & 1023;
        int ic = rem >> 5, oc = rem & 31;
        w2p[(size_t)j*11520 + (kk*32 + oc)*40 + ic] = f2b(W2[i]);
    }
    if(i < 864) w3p[i] = f2b(W3[i]);
}

// ---- partition COO into 8 row-group + 16 col-group streams (per-wave counters) ----
__global__ __launch_bounds__(256) void k_part(const float* __restrict__ vals,
        const int* __restrict__ rows, const int* __restrict__ cols,
        int* bin_pos, uint2* __restrict__ Pst, uint2* __restrict__ Qst){
    __shared__ int cnt[4][24];
    __shared__ int woff[4][24];
    __shared__ int tot[24], start[24], gbase[24];
    __shared__ uint2 stage[4096];
    int t = threadIdx.x, wv = t >> 6;
    if(t < 96) ((int*)cnt)[t] = 0;
    __syncthreads();
    int base = blockIdx.x * 2048;
    int r[8], c[8]; float v[8];
    #pragma unroll
    for(int k = 0; k < 8; k++){
        int e = base + k*256 + t;
        r[k] = rows[e]; c[k] = cols[e]; v[k] = vals[e];
        atomicAdd(&cnt[wv][r[k] >> 10], 1);
        atomicAdd(&cnt[wv][8 + (c[k] >> 10)], 1);
    }
    __syncthreads();
    if(t < 24) tot[t] = cnt[0][t] + cnt[1][t] + cnt[2][t] + cnt[3][t];
    __syncthreads();
    if(t == 0){
        int s = 0;
        for(int q = 0; q < 8; q++){ start[q] = s; s += tot[q]; }
        s = 2048;
        for(int q = 8; q < 24; q++){ start[q] = s; s += tot[q]; }
    }
    if(t < 24) gbase[t] = atomicAdd(&bin_pos[t], tot[t]);
    __syncthreads();
    if(t < 96){
        int w = t / 24, b = t - w*24;
        int off = start[b];
        for(int w2 = 0; w2 < w; w2++) off += cnt[w2][b];
        woff[w][b] = off;
    }
    __syncthreads();
    #pragma unroll
    for(int k = 0; k < 8; k++){
        int pb = r[k] >> 10;
        int p = atomicAdd(&woff[wv][pb], 1);
        stage[p] = make_uint2(((unsigned)(r[k] & 1023) << 14) | (unsigned)c[k],
                              __float_as_uint(v[k]));
        int qb = 8 + (c[k] >> 10);
        int q = atomicAdd(&woff[wv][qb], 1);
        stage[q] = make_uint2(((unsigned)(c[k] & 1023) << 13) | (unsigned)r[k],
                              __float_as_uint(v[k]));
    }
    __syncthreads();
    for(int q = 0; q < 8; q++){
        int len = tot[q];
        uint2* dst = Pst + (size_t)q*PSTRIDE + gbase[q];
        for(int k = t; k < len; k += 256) dst[k] = stage[start[q] + k];
    }
    for(int q = 8; q < 24; q++){
        int len = tot[q];
        uint2* dst = Qst + (size_t)(q-8)*QSTRIDE + gbase[q];
        for(int k = t; k < len; k += 256) dst[k] = stage[start[q] + k];
    }
}

// ---- merged: scat_r | scat_c | init; buckets are 4 B entries (bf16 val | idx) ----
__global__ __launch_bounds__(256) void k_scat(const uint2* __restrict__ Pst,
        const uint2* __restrict__ Qst, const int* __restrict__ bin_pos,
        int* row_cnt, int* col_cnt, unsigned* __restrict__ rp, unsigned* __restrict__ cp,
        const float* __restrict__ z_in, const float* __restrict__ u,
        float* __restrict__ z_cur, float* __restrict__ zu_T){
    __shared__ int cnt[1024], curs[1024];
    int t = threadIdx.x;
    int bid = blockIdx.x;
    if(bid >= 768){          // ---- init branch ----
        int i = (bid - 768)*256 + t;
        int n = i >> 3, b = i & 7;
        float z = z_in[b*Ndim + n];
        z_cur[b*Ndim + n] = z;
        zu_T[i] = z * u[b*Ndim + n];
        return;
    }
    if(bid < 256){           // ---- scatter rows ----
        int g = bid & 7, chunk = bid >> 3;
        int len = bin_pos[g];
        int s0 = (int)(((long long)chunk * len) >> 5);
        int s1 = (int)(((long long)(chunk+1) * len) >> 5);
        for(int i = t; i < 1024; i += 256) cnt[i] = 0;
        __syncthreads();
        const uint2* base = Pst + (size_t)g*PSTRIDE;
        for(int k = s0 + t; k < s1; k += 256)
            atomicAdd(&cnt[base[k].x >> 14], 1);
        __syncthreads();
        for(int i = t; i < 1024; i += 256)
            curs[i] = atomicAdd(&row_cnt[g*1024 + i], cnt[i]);
        __syncthreads();
        for(int k = s0 + t; k < s1; k += 256){
            uint2 e = base[k];
            int r_l = e.x >> 14;
            int slot = atomicAdd(&curs[r_l], 1);
            if(slot < RCAP)
                rp[(size_t)(g*1024 + r_l)*RCAP + slot] =
                    (((unsigned)(unsigned short)f2b(__uint_as_float(e.y))) << 16)
                    | (e.x & 0x3FFFu);
        }
    } else {                 // ---- scatter cols ----
        int bc = bid - 256;
        int g = bc & 15, chunk = bc >> 4;
        int len = bin_pos[8 + g];
        int s0 = (int)(((long long)chunk * len) >> 5);
        int s1 = (int)(((long long)(chunk+1) * len) >> 5);
        for(int i = t; i < 1024; i += 256) cnt[i] = 0;
        __syncthreads();
        const uint2* base = Qst + (size_t)g*QSTRIDE;
        for(int k = s0 + t; k < s1; k += 256)
            atomicAdd(&cnt[base[k].x >> 13], 1);
        __syncthreads();
        for(int i = t; i < 1024; i += 256)
            curs[i] = atomicAdd(&col_cnt[g*1024 + i], cnt[i]);
        __syncthreads();
        for(int k = s0 + t; k < s1; k += 256){
            uint2 e = base[k];
            int c_l = e.x >> 13;
            int slot = atomicAdd(&curs[c_l], 1);
            if(slot < CCAP)
                cp[(size_t)(g*1024 + c_l)*CCAP + slot] =
                    (((unsigned)(unsigned short)f2b(__uint_as_float(e.y))) << 16)
                    | (e.x & 0x1FFFu);
        }
    }
}

// ---- gather-SpMM 1 (+ zero ssq_part[512]) ----
__global__ void k_spmm1g(const unsigned* __restrict__ rp, const int* __restrict__ row_cnt,
                         const float* __restrict__ y, const float* __restrict__ zu_T,
                         float* __restrict__ resid_T, float* __restrict__ ssq_part){
    if(blockIdx.x == 0){
        ssq_part[threadIdx.x] = 0.f;
        ssq_part[256 + threadIdx.x] = 0.f;
    }
    int m = (blockIdx.x*256 + threadIdx.x) >> 6;
    int lane = threadIdx.x & 63;
    int n_nz = min(row_cnt[m], RCAP);
    int b = lane & 7, ks = lane >> 3;
    const unsigned* base = rp + (size_t)m*RCAP;
    float acc = 0.f;
    for(int k = ks*4; k < n_nz; k += 32){
        uint4 e = *(const uint4*)(base + k);
        float w0 = bval(e.x);
        float w1 = (k+1 < n_nz) ? bval(e.y) : 0.f;
        float w2 = (k+2 < n_nz) ? bval(e.z) : 0.f;
        float w3 = (k+3 < n_nz) ? bval(e.w) : 0.f;
        acc = fmaf(w0, zu_T[(e.x & 0x3FFFu)*8 + b], acc);
        acc = fmaf(w1, zu_T[(e.y & 0x3FFFu)*8 + b], acc);
        acc = fmaf(w2, zu_T[(e.z & 0x3FFFu)*8 + b], acc);
        acc = fmaf(w3, zu_T[(e.w & 0x3FFFu)*8 + b], acc);
    }
    acc += __shfl_xor(acc, 8);
    acc += __shfl_xor(acc, 16);
    acc += __shfl_xor(acc, 32);
    if(ks == 0)
        resid_T[m*8 + b] = y[b*Mdim + m] - acc;
}

// ---- gather-SpMM 2 with fused norm partial reduction ----
__global__ void k_spmm2g(const unsigned* __restrict__ cp, const int* __restrict__ col_cnt,
                         const float* __restrict__ resid_T, const float* __restrict__ u,
                         float* __restrict__ v_T, float* __restrict__ ssq_part){
    __shared__ float sred[8];
    int t = threadIdx.x;
    if(t < 8) sred[t] = 0.f;
    __syncthreads();
    int n = (blockIdx.x*256 + t) >> 6;
    int lane = t & 63;
    int n_nz = min(col_cnt[n], CCAP);
    int b = lane & 7, ks = lane >> 3;
    const unsigned* base = cp + (size_t)n*CCAP;
    float acc = 0.f;
    for(int k = ks*4; k < n_nz; k += 32){
        uint4 e = *(const uint4*)(base + k);
        float w0 = bval(e.x);
        float w1 = (k+1 < n_nz) ? bval(e.y) : 0.f;
        float w2 = (k+2 < n_nz) ? bval(e.z) : 0.f;
        float w3 = (k+3 < n_nz) ? bval(e.w) : 0.f;
        acc = fmaf(w0, resid_T[(e.x & 0x1FFFu)*8 + b], acc);
        acc = fmaf(w1, resid_T[(e.y & 0x1FFFu)*8 + b], acc);
        acc = fmaf(w2, resid_T[(e.z & 0x1FFFu)*8 + b], acc);
        acc = fmaf(w3, resid_T[(e.w & 0x1FFFu)*8 + b], acc);
    }
    acc += __shfl_xor(acc, 8);
    acc += __shfl_xor(acc, 16);
    acc += __shfl_xor(acc, 32);
    if(ks == 0){
        v_T[n*8 + b] = acc;
        float uv = u[b*Ndim + n] * acc;
        atomicAdd(&sred[b], uv*uv);
    }
    __syncthreads();
    if(t < 8) atomicAdd(&ssq_part[(blockIdx.x & 63)*8 + t], sred[t]);
}

// ---- fused conv1+conv2+conv3, 4 tiles per block (512 blocks — round-16 proven) ----
__global__ __launch_bounds__(256) void k_conv123(
        const float* __restrict__ z_src, const float* __restrict__ u,
        const float* __restrict__ v_T, const float* __restrict__ ssq_part,
        const float* __restrict__ etas, const float* __restrict__ W1,
        const short* __restrict__ w2p, const short* __restrict__ w3p,
        int j, float* __restrict__ z_dst, float* __restrict__ zu_T){
    __shared__ short w2t[9*32*40];
    __shared__ short x1t[144*40];
    __shared__ short x2t[100*40];
    __shared__ float w1s[288];
    __shared__ short w3b[288];
    __shared__ float r14[196];
    __shared__ float sc_lds;
    int t = threadIdx.x;
    int blk = blockIdx.x;                // 512 blocks: bb = blk>>6, tgroup = blk&63
    int bb = blk >> 6, tgroup = blk & 63;

    for(int idx = t; idx < 1440; idx += 256)
        ((uint4*)w2t)[idx] = ((const uint4*)(w2p + (size_t)j*11520))[idx];
    for(int idx = t; idx < 288; idx += 256){
        w1s[idx] = W1[j*288 + idx];
        w3b[idx] = w3p[j*288 + idx];
    }
    if(t < 64){              // reduce ssq_part -> scale for this sample
        float sv = ssq_part[t*8 + bb];
        #pragma unroll
        for(int off = 32; off > 0; off >>= 1) sv += __shfl_xor(sv, off);
        if(t == 0) sc_lds = etas[j] / fmaxf(1.0f, sqrtf(sv));
    }
    __syncthreads();
    float sc = sc_lds;

    int wv = t >> 6, lane = t & 63, mm = lane & 15, q = lane >> 4;

    for(int tt = 0; tt < 4; tt++){
        int tile = tgroup*4 + tt;
        int oy0 = (tile >> 4)*8, ox0 = (tile & 15)*8;

        if(t < 196){
            int yy = t/14, xx = t%14;
            int gy = oy0 + yy - 3, gx = ox0 + xx - 3;
            float val = 0.f;
            if((unsigned)gy < 128u && (unsigned)gx < 128u){
                int n = gy*IMG + gx;
                int idx = bb*Ndim + n;
                val = z_src[idx] - sc * u[idx] * v_T[n*8 + bb];
            }
            r14[t] = val;
        }
        __syncthreads();

        // conv1 -> x1t bf16
        for(int idx = t; idx < 2304; idx += 256){
            int ocp = idx & 15, p = idx >> 4;
            int py = p/12, px = p%12;
            int gy = oy0 + py - 2, gx = ox0 + px - 2;
            float a0 = 0.f, a1 = 0.f;
            if((unsigned)gy < 128u && (unsigned)gx < 128u){
                #pragma unroll
                for(int ky = 0; ky < 3; ky++)
                    #pragma unroll
                    for(int kx = 0; kx < 3; kx++){
                        float rv = r14[(py+ky)*14 + (px+kx)];
                        a0 = fmaf(rv, w1s[(ky*3+kx)*32 + 2*ocp],     a0);
                        a1 = fmaf(rv, w1s[(ky*3+kx)*32 + 2*ocp + 1], a1);
                    }
                a0 = fmaxf(a0, 0.f); a1 = fmaxf(a1, 0.f);
            }
            unsigned pack = (unsigned short)f2b(a0) | ((unsigned)(unsigned short)f2b(a1) << 16);
            ((unsigned*)x1t)[p*20 + ocp] = pack;
        }
        __syncthreads();

        // conv2 MFMA -> x2t
        #pragma unroll
        for(int rnd = 0; rnd < 2; rnd++){
            int p = rnd*64 + wv*16 + mm;
            int pp = min(p, 99);
            int py2 = pp/10, px2 = pp%10;
            f4_t acc0 = {0.f,0.f,0.f,0.f}, acc1 = {0.f,0.f,0.f,0.f};
            #pragma unroll
            for(int kk = 0; kk < 9; kk++){
                int ky = kk/3, kx = kk%3;
                bf8_t a  = *(const bf8_t*)&x1t[((py2+ky)*12 + (px2+kx))*40 + q*8];
                bf8_t b0 = *(const bf8_t*)&w2t[(kk*32 + mm)*40 + q*8];
                bf8_t b1 = *(const bf8_t*)&w2t[(kk*32 + 16 + mm)*40 + q*8];
                acc0 = __builtin_amdgcn_mfma_f32_16x16x32_bf16(a, b0, acc0, 0, 0, 0);
                acc1 = __builtin_amdgcn_mfma_f32_16x16x32_bf16(a, b1, acc1, 0, 0, 0);
            }
            #pragma unroll
            for(int reg = 0; reg < 4; reg++){
                int pw = rnd*64 + wv*16 + q*4 + reg;
                if(pw < 100){
                    int py = pw/10, px = pw%10;
                    int gy = oy0 + py - 1, gx = ox0 + px - 1;
                    bool in = ((unsigned)gy < 128u) && ((unsigned)gx < 128u);
                    x2t[pw*40 + mm]      = in ? f2b(fmaxf(acc0[reg], 0.f)) : (short)0;
                    x2t[pw*40 + mm + 16] = in ? f2b(fmaxf(acc1[reg], 0.f)) : (short)0;
                }
            }
        }
        __syncthreads();

        // conv3 MFMA (col 0) + epilogue
        int p3 = wv*16 + mm;
        int py3 = p3 >> 3, px3 = p3 & 7;
        f4_t acc = {0.f,0.f,0.f,0.f};
        #pragma unroll
        for(int kk = 0; kk < 9; kk++){
            int ky = kk/3, kx = kk%3;
            bf8_t a = *(const bf8_t*)&x2t[((py3+ky)*10 + (px3+kx))*40 + q*8];
            bf8_t bf;
            #pragma unroll
            for(int jj = 0; jj < 8; jj++)
                bf[jj] = (mm == 0) ? w3b[kk*32 + q*8 + jj] : (short)0;
            acc = __builtin_amdgcn_mfma_f32_16x16x32_bf16(a, bf, acc, 0, 0, 0);
        }
        if(mm == 0){
            #pragma unroll
            for(int reg = 0; reg < 4; reg++){
                int po = wv*16 + q*4 + reg;
                int py = po >> 3, px = po & 7;
                int gy = oy0 + py, gx = ox0 + px;
                int n = gy*IMG + gx;
                int idx = bb*Ndim + n;
                float r = r14[(py+3)*14 + (px+3)];
                float znew = fmaxf(r + acc[reg], 0.f);
                z_dst[idx] = znew;
                zu_T[n*8 + bb] = znew * u[idx];
            }
        }
        __syncthreads();   // protect r14/x1t/x2t reuse next tile
    }
}

extern "C" void kernel_launch(void* const* d_in, const int* in_sizes, int n_in,
                              void* d_out, int out_size, void* d_ws, size_t ws_size,
                              hipStream_t stream){
    const float* A_vals = (const float*)d_in[0];
    const int* A_rows = (const int*)d_in[1];
    const int* A_cols = (const int*)d_in[2];
    const float* z_in = (const float*)d_in[3];
    const float* u    = (const float*)d_in[4];
    const float* y    = (const float*)d_in[5];
    const float* W1   = (const float*)d_in[6];
    const float* W2   = (const float*)d_in[7];
    const float* W3   = (const float*)d_in[8];
    const float* etas = (const float*)d_in[9];

    float* ws = (float*)d_ws;
    float* zA      = ws;  ws += Bsz*Ndim;      // ping
    float* zB      = ws;  ws += Bsz*Ndim;      // pong
    float* zu_T    = ws;  ws += Ndim*8;
    float* v_T     = ws;  ws += Ndim*8;
    float* resid_T = ws;  ws += Mdim*8;
    float* ssq_part= ws;  ws += 512;
    int*   bin_pos = (int*)ws; ws += 32;
    int*   row_cnt = (int*)ws; ws += Mdim;     // col_cnt adjacent after
    int*   col_cnt = (int*)ws; ws += Ndim;
    short* w2p     = (short*)ws; ws += 3*11520/2;
    short* w3p     = (short*)ws; ws += 3*288/2 + 8;
    unsigned* rp = (unsigned*)ws; ws += (size_t)Mdim*RCAP;   // 16.8 MB
    unsigned* cp = (unsigned*)ws; ws += (size_t)Ndim*CCAP;   // 16.8 MB
    uint2* Pst = (uint2*)ws;  ws += (size_t)8*PSTRIDE*2;     // 17.3 MB
    uint2* Qst = (uint2*)ws;                                  // 17.3 MB

    k_prep<<<108, 256, 0, stream>>>(W2, W3, w2p, w3p, bin_pos, row_cnt);
    k_part<<<Ennz/2048, 256, 0, stream>>>(A_vals, A_rows, A_cols, bin_pos, Pst, Qst);
    k_scat<<<1280, 256, 0, stream>>>(Pst, Qst, bin_pos, row_cnt, col_cnt, rp, cp,
                                     z_in, u, zA, zu_T);

    for(int j = 0; j < Jit; j++){
        k_spmm1g<<<Mdim/4, 256, 0, stream>>>(rp, row_cnt, y, zu_T, resid_T, ssq_part);
        k_spmm2g<<<Ndim/4, 256, 0, stream>>>(cp, col_cnt, resid_T, u, v_T, ssq_part);
        const float* zsrc = (j & 1) ? zB : zA;           // j=0:A, j=1:B, j=2:A
        float* zdst = (j == Jit-1) ? (float*)d_out : ((j & 1) ? zA : zB);
        k_conv123<<<512, 256, 0, stream>>>(zsrc, u, v_T, ssq_part, etas,
                                           W1, w2p, w3p, j, zdst, zu_T);
    }
}

// Round 19
// 308.687 us; speedup vs baseline: 1.0320x; 1.0167x over previous
//
#include <hip/hip_runtime.h>
#include <hip/hip_bf16.h>

#define Mdim 8192
#define Ndim 16384
#define Ennz 2097152
#define Bsz 8
#define Jit 3
#define IMG 128
#define RCAP 512
#define CCAP 256
#define EPB 4096         // entries per k_part block
#define PSTRIDE 270336   // E/8 + slack
#define QSTRIDE 135168   // E/16 + slack

typedef __attribute__((ext_vector_type(8))) short bf8_t;
typedef __attribute__((ext_vector_type(4))) float f4_t;

__device__ __forceinline__ short f2b(float f){
    __hip_bfloat16 h = __float2bfloat16(f);
    return *reinterpret_cast<short*>(&h);
}
__device__ __forceinline__ float bval(unsigned e){
    return __uint_as_float(e & 0xFFFF0000u);
}

// ---- prep: bf16 weight conversion + zero all counters ----
__global__ void k_prep(const float* __restrict__ W2, const float* __restrict__ W3,
                       short* __restrict__ w2p, short* __restrict__ w3p,
                       int* bin_pos, int* cnts){
    int i = blockIdx.x*256 + threadIdx.x;     // grid 108*256 = 27648
    if(i < 24) bin_pos[i] = 0;
    if(i < 24576) cnts[i] = 0;                // row_cnt(8192)+col_cnt(16384) adjacent
    if(i < 27648){
        int j = i / 9216, idx = i - j*9216;
        int kk = idx >> 10, rem = idx & 1023;
        int ic = rem >> 5, oc = rem & 31;
        w2p[(size_t)j*11520 + (kk*32 + oc)*40 + ic] = f2b(W2[i]);
    }
    if(i < 864) w3p[i] = f2b(W3[i]);
}

// ---- partition COO into 8 row-group + 16 col-group streams.
// 4096 entries/block: doubled run lengths keep the 256-wide copy loops full.
__global__ __launch_bounds__(256) void k_part(const float* __restrict__ vals,
        const int* __restrict__ rows, const int* __restrict__ cols,
        int* bin_pos, uint2* __restrict__ Pst, uint2* __restrict__ Qst){
    __shared__ int cnt[4][24];
    __shared__ int woff[4][24];
    __shared__ int tot[24], start[24], gbase[24];
    __shared__ uint2 stage[2*EPB];       // 64 KB
    int t = threadIdx.x, wv = t >> 6;
    if(t < 96) ((int*)cnt)[t] = 0;
    __syncthreads();
    int base = blockIdx.x * EPB;
    int r[16], c[16]; float v[16];
    #pragma unroll
    for(int k = 0; k < 16; k++){
        int e = base + k*256 + t;
        r[k] = rows[e]; c[k] = cols[e]; v[k] = vals[e];
        atomicAdd(&cnt[wv][r[k] >> 10], 1);
        atomicAdd(&cnt[wv][8 + (c[k] >> 10)], 1);
    }
    __syncthreads();
    if(t < 24) tot[t] = cnt[0][t] + cnt[1][t] + cnt[2][t] + cnt[3][t];
    __syncthreads();
    if(t == 0){
        int s = 0;
        for(int q = 0; q < 8; q++){ start[q] = s; s += tot[q]; }
        s = EPB;
        for(int q = 8; q < 24; q++){ start[q] = s; s += tot[q]; }
    }
    if(t < 24) gbase[t] = atomicAdd(&bin_pos[t], tot[t]);
    __syncthreads();
    if(t < 96){
        int w = t / 24, b = t - w*24;
        int off = start[b];
        for(int w2 = 0; w2 < w; w2++) off += cnt[w2][b];
        woff[w][b] = off;
    }
    __syncthreads();
    #pragma unroll
    for(int k = 0; k < 16; k++){
        int pb = r[k] >> 10;
        int p = atomicAdd(&woff[wv][pb], 1);
        stage[p] = make_uint2(((unsigned)(r[k] & 1023) << 14) | (unsigned)c[k],
                              __float_as_uint(v[k]));
        int qb = 8 + (c[k] >> 10);
        int q = atomicAdd(&woff[wv][qb], 1);
        stage[q] = make_uint2(((unsigned)(c[k] & 1023) << 13) | (unsigned)r[k],
                              __float_as_uint(v[k]));
    }
    __syncthreads();
    for(int q = 0; q < 8; q++){
        int len = tot[q];
        uint2* dst = Pst + (size_t)q*PSTRIDE + gbase[q];
        for(int k = t; k < len; k += 256) dst[k] = stage[start[q] + k];
    }
    for(int q = 8; q < 24; q++){
        int len = tot[q];
        uint2* dst = Qst + (size_t)(q-8)*QSTRIDE + gbase[q];
        for(int k = t; k < len; k += 256) dst[k] = stage[start[q] + k];
    }
}

// ---- merged: scat_r | scat_c | init; buckets are 4 B entries (bf16 val | idx) ----
__global__ __launch_bounds__(256) void k_scat(const uint2* __restrict__ Pst,
        const uint2* __restrict__ Qst, const int* __restrict__ bin_pos,
        int* row_cnt, int* col_cnt, unsigned* __restrict__ rp, unsigned* __restrict__ cp,
        const float* __restrict__ z_in, const float* __restrict__ u,
        float* __restrict__ z_cur, float* __restrict__ zu_T){
    __shared__ int cnt[1024], curs[1024];
    int t = threadIdx.x;
    int bid = blockIdx.x;
    if(bid >= 768){          // ---- init branch ----
        int i = (bid - 768)*256 + t;
        int n = i >> 3, b = i & 7;
        float z = z_in[b*Ndim + n];
        z_cur[b*Ndim + n] = z;
        zu_T[i] = z * u[b*Ndim + n];
        return;
    }
    if(bid < 256){           // ---- scatter rows ----
        int g = bid & 7, chunk = bid >> 3;
        int len = bin_pos[g];
        int s0 = (int)(((long long)chunk * len) >> 5);
        int s1 = (int)(((long long)(chunk+1) * len) >> 5);
        for(int i = t; i < 1024; i += 256) cnt[i] = 0;
        __syncthreads();
        const uint2* base = Pst + (size_t)g*PSTRIDE;
        for(int k = s0 + t; k < s1; k += 256)
            atomicAdd(&cnt[base[k].x >> 14], 1);
        __syncthreads();
        for(int i = t; i < 1024; i += 256)
            curs[i] = atomicAdd(&row_cnt[g*1024 + i], cnt[i]);
        __syncthreads();
        for(int k = s0 + t; k < s1; k += 256){
            uint2 e = base[k];
            int r_l = e.x >> 14;
            int slot = atomicAdd(&curs[r_l], 1);
            if(slot < RCAP)
                rp[(size_t)(g*1024 + r_l)*RCAP + slot] =
                    (((unsigned)(unsigned short)f2b(__uint_as_float(e.y))) << 16)
                    | (e.x & 0x3FFFu);
        }
    } else {                 // ---- scatter cols ----
        int bc = bid - 256;
        int g = bc & 15, chunk = bc >> 4;
        int len = bin_pos[8 + g];
        int s0 = (int)(((long long)chunk * len) >> 5);
        int s1 = (int)(((long long)(chunk+1) * len) >> 5);
        for(int i = t; i < 1024; i += 256) cnt[i] = 0;
        __syncthreads();
        const uint2* base = Qst + (size_t)g*QSTRIDE;
        for(int k = s0 + t; k < s1; k += 256)
            atomicAdd(&cnt[base[k].x >> 13], 1);
        __syncthreads();
        for(int i = t; i < 1024; i += 256)
            curs[i] = atomicAdd(&col_cnt[g*1024 + i], cnt[i]);
        __syncthreads();
        for(int k = s0 + t; k < s1; k += 256){
            uint2 e = base[k];
            int c_l = e.x >> 13;
            int slot = atomicAdd(&curs[c_l], 1);
            if(slot < CCAP)
                cp[(size_t)(g*1024 + c_l)*CCAP + slot] =
                    (((unsigned)(unsigned short)f2b(__uint_as_float(e.y))) << 16)
                    | (e.x & 0x1FFFu);
        }
    }
}

// ---- gather-SpMM 1 (+ zero ssq_part[512]) ----
__global__ void k_spmm1g(const unsigned* __restrict__ rp, const int* __restrict__ row_cnt,
                         const float* __restrict__ y, const float* __restrict__ zu_T,
                         float* __restrict__ resid_T, float* __restrict__ ssq_part){
    if(blockIdx.x == 0){
        ssq_part[threadIdx.x] = 0.f;
        ssq_part[256 + threadIdx.x] = 0.f;
    }
    int m = (blockIdx.x*256 + threadIdx.x) >> 6;
    int lane = threadIdx.x & 63;
    int n_nz = min(row_cnt[m], RCAP);
    int b = lane & 7, ks = lane >> 3;
    const unsigned* base = rp + (size_t)m*RCAP;
    float acc = 0.f;
    for(int k = ks*4; k < n_nz; k += 32){
        uint4 e = *(const uint4*)(base + k);
        float w0 = bval(e.x);
        float w1 = (k+1 < n_nz) ? bval(e.y) : 0.f;
        float w2 = (k+2 < n_nz) ? bval(e.z) : 0.f;
        float w3 = (k+3 < n_nz) ? bval(e.w) : 0.f;
        acc = fmaf(w0, zu_T[(e.x & 0x3FFFu)*8 + b], acc);
        acc = fmaf(w1, zu_T[(e.y & 0x3FFFu)*8 + b], acc);
        acc = fmaf(w2, zu_T[(e.z & 0x3FFFu)*8 + b], acc);
        acc = fmaf(w3, zu_T[(e.w & 0x3FFFu)*8 + b], acc);
    }
    acc += __shfl_xor(acc, 8);
    acc += __shfl_xor(acc, 16);
    acc += __shfl_xor(acc, 32);
    if(ks == 0)
        resid_T[m*8 + b] = y[b*Mdim + m] - acc;
}

// ---- gather-SpMM 2 with fused norm partial reduction ----
__global__ void k_spmm2g(const unsigned* __restrict__ cp, const int* __restrict__ col_cnt,
                         const float* __restrict__ resid_T, const float* __restrict__ u,
                         float* __restrict__ v_T, float* __restrict__ ssq_part){
    __shared__ float sred[8];
    int t = threadIdx.x;
    if(t < 8) sred[t] = 0.f;
    __syncthreads();
    int n = (blockIdx.x*256 + t) >> 6;
    int lane = t & 63;
    int n_nz = min(col_cnt[n], CCAP);
    int b = lane & 7, ks = lane >> 3;
    const unsigned* base = cp + (size_t)n*CCAP;
    float acc = 0.f;
    for(int k = ks*4; k < n_nz; k += 32){
        uint4 e = *(const uint4*)(base + k);
        float w0 = bval(e.x);
        float w1 = (k+1 < n_nz) ? bval(e.y) : 0.f;
        float w2 = (k+2 < n_nz) ? bval(e.z) : 0.f;
        float w3 = (k+3 < n_nz) ? bval(e.w) : 0.f;
        acc = fmaf(w0, resid_T[(e.x & 0x1FFFu)*8 + b], acc);
        acc = fmaf(w1, resid_T[(e.y & 0x1FFFu)*8 + b], acc);
        acc = fmaf(w2, resid_T[(e.z & 0x1FFFu)*8 + b], acc);
        acc = fmaf(w3, resid_T[(e.w & 0x1FFFu)*8 + b], acc);
    }
    acc += __shfl_xor(acc, 8);
    acc += __shfl_xor(acc, 16);
    acc += __shfl_xor(acc, 32);
    if(ks == 0){
        v_T[n*8 + b] = acc;
        float uv = u[b*Ndim + n] * acc;
        atomicAdd(&sred[b], uv*uv);
    }
    __syncthreads();
    if(t < 8) atomicAdd(&ssq_part[(blockIdx.x & 63)*8 + t], sred[t]);
}

// ---- fused conv1+conv2+conv3, 4 tiles per block; float4 z epilogue ----
__global__ __launch_bounds__(256) void k_conv123(
        const float* __restrict__ z_src, const float* __restrict__ u,
        const float* __restrict__ v_T, const float* __restrict__ ssq_part,
        const float* __restrict__ etas, const float* __restrict__ W1,
        const short* __restrict__ w2p, const short* __restrict__ w3p,
        int j, float* __restrict__ z_dst, float* __restrict__ zu_T){
    __shared__ short w2t[9*32*40];
    __shared__ short x1t[144*40];
    __shared__ short x2t[100*40];
    __shared__ float w1s[288];
    __shared__ short w3b[288];
    __shared__ float r14[196];
    __shared__ float sc_lds;
    int t = threadIdx.x;
    int blk = blockIdx.x;                // 512 blocks: bb = blk>>6, tgroup = blk&63
    int bb = blk >> 6, tgroup = blk & 63;

    for(int idx = t; idx < 1440; idx += 256)
        ((uint4*)w2t)[idx] = ((const uint4*)(w2p + (size_t)j*11520))[idx];
    for(int idx = t; idx < 288; idx += 256){
        w1s[idx] = W1[j*288 + idx];
        w3b[idx] = w3p[j*288 + idx];
    }
    if(t < 64){              // reduce ssq_part -> scale for this sample
        float sv = ssq_part[t*8 + bb];
        #pragma unroll
        for(int off = 32; off > 0; off >>= 1) sv += __shfl_xor(sv, off);
        if(t == 0) sc_lds = etas[j] / fmaxf(1.0f, sqrtf(sv));
    }
    __syncthreads();
    float sc = sc_lds;

    int wv = t >> 6, lane = t & 63, mm = lane & 15, q = lane >> 4;

    for(int tt = 0; tt < 4; tt++){
        int tile = tgroup*4 + tt;
        int oy0 = (tile >> 4)*8, ox0 = (tile & 15)*8;

        if(t < 196){
            int yy = t/14, xx = t%14;
            int gy = oy0 + yy - 3, gx = ox0 + xx - 3;
            float val = 0.f;
            if((unsigned)gy < 128u && (unsigned)gx < 128u){
                int n = gy*IMG + gx;
                int idx = bb*Ndim + n;
                val = z_src[idx] - sc * u[idx] * v_T[n*8 + bb];
            }
            r14[t] = val;
        }
        __syncthreads();

        // conv1 -> x1t bf16
        for(int idx = t; idx < 2304; idx += 256){
            int ocp = idx & 15, p = idx >> 4;
            int py = p/12, px = p%12;
            int gy = oy0 + py - 2, gx = ox0 + px - 2;
            float a0 = 0.f, a1 = 0.f;
            if((unsigned)gy < 128u && (unsigned)gx < 128u){
                #pragma unroll
                for(int ky = 0; ky < 3; ky++)
                    #pragma unroll
                    for(int kx = 0; kx < 3; kx++){
                        float rv = r14[(py+ky)*14 + (px+kx)];
                        a0 = fmaf(rv, w1s[(ky*3+kx)*32 + 2*ocp],     a0);
                        a1 = fmaf(rv, w1s[(ky*3+kx)*32 + 2*ocp + 1], a1);
                    }
                a0 = fmaxf(a0, 0.f); a1 = fmaxf(a1, 0.f);
            }
            unsigned pack = (unsigned short)f2b(a0) | ((unsigned)(unsigned short)f2b(a1) << 16);
            ((unsigned*)x1t)[p*20 + ocp] = pack;
        }
        __syncthreads();

        // conv2 MFMA -> x2t
        #pragma unroll
        for(int rnd = 0; rnd < 2; rnd++){
            int p = rnd*64 + wv*16 + mm;
            int pp = min(p, 99);
            int py2 = pp/10, px2 = pp%10;
            f4_t acc0 = {0.f,0.f,0.f,0.f}, acc1 = {0.f,0.f,0.f,0.f};
            #pragma unroll
            for(int kk = 0; kk < 9; kk++){
                int ky = kk/3, kx = kk%3;
                bf8_t a  = *(const bf8_t*)&x1t[((py2+ky)*12 + (px2+kx))*40 + q*8];
                bf8_t b0 = *(const bf8_t*)&w2t[(kk*32 + mm)*40 + q*8];
                bf8_t b1 = *(const bf8_t*)&w2t[(kk*32 + 16 + mm)*40 + q*8];
                acc0 = __builtin_amdgcn_mfma_f32_16x16x32_bf16(a, b0, acc0, 0, 0, 0);
                acc1 = __builtin_amdgcn_mfma_f32_16x16x32_bf16(a, b1, acc1, 0, 0, 0);
            }
            #pragma unroll
            for(int reg = 0; reg < 4; reg++){
                int pw = rnd*64 + wv*16 + q*4 + reg;
                if(pw < 100){
                    int py = pw/10, px = pw%10;
                    int gy = oy0 + py - 1, gx = ox0 + px - 1;
                    bool in = ((unsigned)gy < 128u) && ((unsigned)gx < 128u);
                    x2t[pw*40 + mm]      = in ? f2b(fmaxf(acc0[reg], 0.f)) : (short)0;
                    x2t[pw*40 + mm + 16] = in ? f2b(fmaxf(acc1[reg], 0.f)) : (short)0;
                }
            }
        }
        __syncthreads();

        // conv3 MFMA (col 0) + epilogue (float4 z write; zu_T scalar scatter)
        int p3 = wv*16 + mm;
        int py3 = p3 >> 3, px3 = p3 & 7;
        f4_t acc = {0.f,0.f,0.f,0.f};
        #pragma unroll
        for(int kk = 0; kk < 9; kk++){
            int ky = kk/3, kx = kk%3;
            bf8_t a = *(const bf8_t*)&x2t[((py3+ky)*10 + (px3+kx))*40 + q*8];
            bf8_t bf;
            #pragma unroll
            for(int jj = 0; jj < 8; jj++)
                bf[jj] = (mm == 0) ? w3b[kk*32 + q*8 + jj] : (short)0;
            acc = __builtin_amdgcn_mfma_f32_16x16x32_bf16(a, bf, acc, 0, 0, 0);
        }
        if(mm == 0){
            // po = wv*16 + q*4 + reg -> py = wv*2 + (q>>1), px = (q&1)*4 + reg
            int py = wv*2 + (q >> 1);
            int gx0 = ox0 + (q & 1)*4;
            int gy = oy0 + py;
            int n0 = gy*IMG + gx0;
            float4 zq;
            float zr[4];
            #pragma unroll
            for(int reg = 0; reg < 4; reg++){
                float r = r14[(py+3)*14 + ((q&1)*4 + reg + 3)];
                zr[reg] = fmaxf(r + acc[reg], 0.f);
            }
            zq.x = zr[0]; zq.y = zr[1]; zq.z = zr[2]; zq.w = zr[3];
            *(float4*)(z_dst + bb*Ndim + n0) = zq;
            #pragma unroll
            for(int reg = 0; reg < 4; reg++)
                zu_T[(n0 + reg)*8 + bb] = zr[reg] * u[bb*Ndim + n0 + reg];
        }
        __syncthreads();   // protect r14/x1t/x2t reuse next tile
    }
}

extern "C" void kernel_launch(void* const* d_in, const int* in_sizes, int n_in,
                              void* d_out, int out_size, void* d_ws, size_t ws_size,
                              hipStream_t stream){
    const float* A_vals = (const float*)d_in[0];
    const int* A_rows = (const int*)d_in[1];
    const int* A_cols = (const int*)d_in[2];
    const float* z_in = (const float*)d_in[3];
    const float* u    = (const float*)d_in[4];
    const float* y    = (const float*)d_in[5];
    const float* W1   = (const float*)d_in[6];
    const float* W2   = (const float*)d_in[7];
    const float* W3   = (const float*)d_in[8];
    const float* etas = (const float*)d_in[9];

    float* ws = (float*)d_ws;
    float* zA      = ws;  ws += Bsz*Ndim;      // ping
    float* zB      = ws;  ws += Bsz*Ndim;      // pong
    float* zu_T    = ws;  ws += Ndim*8;
    float* v_T     = ws;  ws += Ndim*8;
    float* resid_T = ws;  ws += Mdim*8;
    float* ssq_part= ws;  ws += 512;
    int*   bin_pos = (int*)ws; ws += 32;
    int*   row_cnt = (int*)ws; ws += Mdim;     // col_cnt adjacent after
    int*   col_cnt = (int*)ws; ws += Ndim;
    short* w2p     = (short*)ws; ws += 3*11520/2;
    short* w3p     = (short*)ws; ws += 3*288/2 + 8;
    unsigned* rp = (unsigned*)ws; ws += (size_t)Mdim*RCAP;   // 16.8 MB
    unsigned* cp = (unsigned*)ws; ws += (size_t)Ndim*CCAP;   // 16.8 MB
    uint2* Pst = (uint2*)ws;  ws += (size_t)8*PSTRIDE*2;     // 17.3 MB
    uint2* Qst = (uint2*)ws;                                  // 17.3 MB

    k_prep<<<108, 256, 0, stream>>>(W2, W3, w2p, w3p, bin_pos, row_cnt);
    k_part<<<Ennz/EPB, 256, 0, stream>>>(A_vals, A_rows, A_cols, bin_pos, Pst, Qst);
    k_scat<<<1280, 256, 0, stream>>>(Pst, Qst, bin_pos, row_cnt, col_cnt, rp, cp,
                                     z_in, u, zA, zu_T);

    for(int j = 0; j < Jit; j++){
        k_spmm1g<<<Mdim/4, 256, 0, stream>>>(rp, row_cnt, y, zu_T, resid_T, ssq_part);
        k_spmm2g<<<Ndim/4, 256, 0, stream>>>(cp, col_cnt, resid_T, u, v_T, ssq_part);
        const float* zsrc = (j & 1) ? zB : zA;           // j=0:A, j=1:B, j=2:A
        float* zdst = (j == Jit-1) ? (float*)d_out : ((j & 1) ? zA : zB);
        k_conv123<<<512, 256, 0, stream>>>(zsrc, u, v_T, ssq_part, etas,
                                           W1, w2p, w3p, j, zdst, zu_T);
    }
}